// Round 10
// baseline (806.998 us; speedup 1.0000x reference)
//
#include <hip/hip_runtime.h>
#include <hip/hip_bf16.h>

// ---------------------------------------------------------------------------
// EfficientVQBlock — round 9: k_codes via wave-uniform SGPR codebook loads.
//  * Round-8/9 lesson: 32KB-LDS codebook caps residency (~8 waves/CU) and the
//    scan stalls on dep chains + uniform ds_read bursts (213us, floor ~55us).
//  * k_codes v3: codebook rows read with all-uniform indices -> s_load into
//    SGPRs (same trick that fixed k_qkv); LDS = 1KB (cc32 broadcast only);
//    2 fp32 accum chains per role; fp64 top-2 refine reads global cb.
//    Argmin remains fp64-exact -> absmax must stay 0.03125.
//  * Everything else verbatim from round 9 pass.
//
// Workspace layout identical to round 7/8/9 (proven, peak 134 MB).
// ---------------------------------------------------------------------------

typedef __hip_bfloat16 bf16;
typedef float  v4f __attribute__((ext_vector_type(4)));
typedef short  v8s __attribute__((ext_vector_type(8)));

#define DEV static __device__ __forceinline__
DEV float b2f(const bf16 v) { return __bfloat162float(v); }

#define CIN  256
#define NN   1024
#define O1   768
#define DD   32
#define KK   256
#define EE   1024

// ==================== K0: w_qkv fp32 -> fp64 (for SGPR path) ================
__global__ __launch_bounds__(256) void k_cvt64(const float* __restrict__ w,
                                               double* __restrict__ w64) {
    int i = blockIdx.x * 256 + threadIdx.x;          // 196608
    w64[i] = (double)w[i];
}

// ============================ K1: qkv fp64 GEMM =============================
__global__ __launch_bounds__(256) void k_qkv(const float* __restrict__ x,
                                             const double* __restrict__ w64,
                                             float* __restrict__ qkvf) {
    int t  = threadIdx.x;
    int p  = blockIdx.x * 256 + t;
    int o0 = blockIdx.y * 32;
    int b  = blockIdx.z;
    const float*  xb = x + ((size_t)b * CIN << 10) + p;
    const double* wb = w64 + (size_t)o0 * CIN;

    double acc[32];
#pragma unroll
    for (int i = 0; i < 32; ++i) acc[i] = 0.0;

    for (int c0 = 0; c0 < CIN; c0 += 8) {
        double xr[8];
#pragma unroll
        for (int cc = 0; cc < 8; ++cc)
            xr[cc] = (double)xb[(size_t)(c0 + cc) << 10];
#pragma unroll
        for (int oo = 0; oo < 32; ++oo) {
#pragma unroll
            for (int cc = 0; cc < 8; ++cc)
                acc[oo] += xr[cc] * wb[oo * CIN + c0 + cc];   // uniform -> s_load
        }
    }
#pragma unroll
    for (int oo = 0; oo < 32; ++oo)
        qkvf[(((size_t)b * O1 + o0 + oo) << 10) + p] = (float)acc[oo];
}

// ======================= K2: depthwise 5x5 fp64, staged =====================
__global__ __launch_bounds__(256) void k_dw5(const float* __restrict__ qkvf,
                                             const float* __restrict__ w5,
                                             float* __restrict__ dwb) {
    __shared__ float  xs[12][32];
    __shared__ double wd[25];
    int t  = threadIdx.x;
    int rg = blockIdx.x;
    int o  = blockIdx.y;
    int b  = blockIdx.z;
    int r0 = rg * 8;
    const float* src = qkvf + (((size_t)b * O1 + o) << 10);
    for (int i = t; i < 384; i += 256) {
        int lr = i >> 5, c = i & 31;
        int ry = r0 + lr - 2;
        xs[lr][c] = (ry >= 0 && ry < 32) ? src[ry * 32 + c] : 0.0f;
    }
    if (t < 25) wd[t] = (double)w5[o * 25 + t];
    __syncthreads();
    int row = t >> 5, col = t & 31;
    double acc = 0.0;
#pragma unroll
    for (int dy = 0; dy < 5; ++dy) {
#pragma unroll
        for (int dx = 0; dx < 5; ++dx) {
            int c = col + dx - 2;
            if (c >= 0 && c < 32)
                acc += (double)xs[row + dy][c] * wd[dy * 5 + dx];
        }
    }
    dwb[(((size_t)b * O1 + o) << 10) + (r0 + row) * 32 + col] = (float)acc;
}

// ===================== K3: grouped 1x1 (24 x 32->32) fp64 ===================
__global__ __launch_bounds__(256) void k_gpw(const float* __restrict__ dwb,
                                             const float* __restrict__ w,
                                             float* __restrict__ agg) {
    __shared__ double wld[1024];
    int t  = threadIdx.x;
    int p  = blockIdx.x * 256 + t;
    int g  = blockIdx.y;
    int b  = blockIdx.z;
#pragma unroll
    for (int i = 0; i < 4; ++i)
        wld[i * 256 + t] = (double)w[g * 1024 + i * 256 + t];
    __syncthreads();
    double x64[32];
#pragma unroll
    for (int i = 0; i < 32; ++i)
        x64[i] = (double)dwb[(((size_t)b * O1 + g * 32 + i) << 10) + p];
#pragma unroll
    for (int oo = 0; oo < 32; ++oo) {
        double acc = 0.0;
#pragma unroll
        for (int i2 = 0; i2 < 16; ++i2) {
            double2 wv = *(const double2*)&wld[oo * 32 + 2 * i2];
            acc += x64[2 * i2] * wv.x + x64[2 * i2 + 1] * wv.y;
        }
        agg[(((size_t)b * O1 + g * 32 + oo) << 10) + p] = (float)acc;
    }
}

// ====== K4: VQ argmin (SGPR-codebook fp32 scan + fp64 top-2 refine) =========
// dref: cc - 2*dot in fp64 from GLOBAL codebook (constant |v|^2 dropped ->
// equal shift, ordering + tie-break identical).
DEV double dref_g(const float* v, const float* __restrict__ cb, int c) {
    double dot = 0.0, cc = 0.0;
#pragma unroll
    for (int d = 0; d < DD; ++d) {
        double cd = (double)cb[(c << 5) + d];
        dot += (double)v[d] * cd;
        cc  += cd * cd;
    }
    return cc - 2.0 * dot;
}
DEV int refine2g(const float* v, const float* __restrict__ cb, int i1, int i2) {
    double e1 = dref_g(v, cb, i1);
    double e2 = dref_g(v, cb, i2);
    return (e2 < e1 || (e2 == e1 && i2 < i1)) ? i2 : i1;
}

// 1024 blocks x 256 threads: blk>>2 = bm, (blk&3)*256+t = pixel. LDS = 1KB.
__global__ __launch_bounds__(256) void k_codes(const float* __restrict__ qkvf,
                                               const float* __restrict__ agg,
                                               const float* __restrict__ cb,
                                               int* __restrict__ qi,
                                               int* __restrict__ ki) {
    __shared__ float cc32[KK];       // 1 KB only
    int t   = threadIdx.x;
    int blk = blockIdx.x;
    int bm  = blk >> 2;
    int mg  = bm & 15, b = bm >> 4;
    int n   = ((blk & 3) << 8) + t;

    {   // cc32[t]: fp64 accum from global codebook (L1-hot after first block)
        double s = 0.0;
#pragma unroll
        for (int d = 0; d < DD; ++d) {
            double v = (double)cb[(t << 5) + d];
            s += v * v;
        }
        cc32[t] = (float)s;
    }
    __syncthreads();

    int cm = mg * 96;
    const float* src = (cm < O1) ? qkvf + (((size_t)b * O1 + cm) << 10)
                                 : agg  + (((size_t)b * O1 + cm - O1) << 10);
    float q[DD], k[DD];
#pragma unroll
    for (int d = 0; d < DD; ++d) {
        q[d] = src[((size_t)d << 10) + n];
        k[d] = src[((size_t)(DD + d) << 10) + n];
    }

    float d1q = 3.4e38f, d2q = 3.4e38f, d1k = 3.4e38f, d2k = 3.4e38f;
    int   i1q = 0, i2q = 1, i1k = 0, i2k = 1;
    for (int c = 0; c < KK; ++c) {
        const float* cr = cb + (c << 5);             // uniform -> s_load row
        float q0 = 0.0f, q1 = 0.0f, k0 = 0.0f, k1 = 0.0f;  // 2 chains/role
#pragma unroll
        for (int d = 0; d < DD; d += 2) {
            float c0 = cr[d], c1 = cr[d + 1];        // SGPR operands
            q0 = fmaf(q[d],     c0, q0);
            k0 = fmaf(k[d],     c0, k0);
            q1 = fmaf(q[d + 1], c1, q1);
            k1 = fmaf(k[d + 1], c1, k1);
        }
        float cc = cc32[c];                          // LDS broadcast
        float ddq = cc - 2.0f * (q0 + q1);
        float ddk = cc - 2.0f * (k0 + k1);
        if (ddq < d1q)      { d2q = d1q; i2q = i1q; d1q = ddq; i1q = c; }
        else if (ddq < d2q) { d2q = ddq; i2q = c; }
        if (ddk < d1k)      { d2k = d1k; i2k = i1k; d1k = ddk; i1k = c; }
        else if (ddk < d2k) { d2k = ddk; i2k = c; }
    }
    qi[((size_t)bm << 10) + n] = (i1q == i2q) ? i1q : refine2g(q, cb, i1q, i2q);
    ki[((size_t)bm << 10) + n] = (i1k == i2k) ? i1k : refine2g(k, cb, i1k, i2k);
}

// ================ K5: scatter v by k-code into LDS buckets ==================
// Rotated bucket layout -> atomic bank = (d+bk)%32 (spreads lanes over banks).
__global__ __launch_bounds__(512) void k_scatter(const float* __restrict__ qkvf,
                                                 const float* __restrict__ agg,
                                                 const int* __restrict__ ki,
                                                 float* __restrict__ bucket) {
    __shared__ float sums[KK * DD];  // 32 KB
    __shared__ int   cnt[KK];        //  1 KB
    int t  = threadIdx.x;
    int bm = blockIdx.x;
    int mg = bm & 15, b = bm >> 4;
    for (int i = t; i < KK * DD; i += 512) sums[i] = 0.0f;
    if (t < KK) cnt[t] = 0;
    __syncthreads();

    int cm = mg * 96;
    const float* src = (cm < O1) ? qkvf + (((size_t)b * O1 + cm) << 10)
                                 : agg  + (((size_t)b * O1 + cm - O1) << 10);
    for (int i = 0; i < 2; ++i) {
        int n = i * 512 + t;
        int bk = ki[((size_t)bm << 10) + n] & 255;   // defensive mask
#pragma unroll
        for (int d = 0; d < DD; ++d)
            atomicAdd(&sums[(bk << 5) | ((d + bk) & 31)],
                      src[((size_t)(2 * DD + d) << 10) + n]);
        atomicAdd(&cnt[bk], 1);
    }
    __syncthreads();
    for (int i = t; i < KK * DD; i += 512) {
        int bkt_i = i >> 5, d = i & 31;
        float s = sums[(i & ~31) | ((d + bkt_i) & 31)];   // un-rotate
        float c = (float)cnt[bkt_i];
        bucket[((size_t)bm << 13) + i] = s / fmaxf(c, 1.0f);
    }
}

// ================= K6: cast GEMM weights fp32 -> bf16 =======================
__global__ __launch_bounds__(256) void k_cvt(const float* __restrict__ wp,
                                             const float* __restrict__ we,
                                             const float* __restrict__ ww,
                                             bf16* __restrict__ wbp,
                                             bf16* __restrict__ wbe,
                                             bf16* __restrict__ wbw) {
    int i = blockIdx.x * 256 + threadIdx.x;          // 655360
    if (i < 131072)       wbp[i] = __float2bfloat16(wp[i]);
    else if (i < 393216)  wbe[i - 131072] = __float2bfloat16(we[i - 131072]);
    else                  wbw[i - 393216] = __float2bfloat16(ww[i - 393216]);
}

// ================= K7: gather buckets by q-code -> vout bf16 ================
__global__ __launch_bounds__(256) void k_gather(const float* __restrict__ bucket,
                                                const int* __restrict__ qi,
                                                bf16* __restrict__ vout) {
    int idx = blockIdx.x * 256 + threadIdx.x;        // 16*512*1024
    int p  = idx & (NN - 1);
    int ch = (idx >> 10) & 511;
    int b  = idx >> 19;
    int mg = ch >> 5, d = ch & 31;
    int bm = b * 16 + mg;
    int code = qi[((size_t)bm << 10) + p] & 255;     // defensive mask
    vout[idx] = __float2bfloat16(bucket[((size_t)bm << 13) + code * DD + d]);
}

// ===================== shared bf16 MFMA GEMM core (64x64) ===================
#define LDSPITCH 40

DEV void gemm_core(const bf16* __restrict__ A, const bf16* __restrict__ B,
                   int K, int M0, int N0, int t, bf16* As, bf16* Bs, v4f* acc) {
    int ma = t >> 2, ka = (t & 3) * 8;
    int kb = t & 31, nb = (t >> 5) * 8;
    int l = t & 63, w = t >> 6;
    for (int k0 = 0; k0 < K; k0 += 32) {
        __syncthreads();
        *(uint4*)&As[ma * LDSPITCH + ka] =
            *(const uint4*)&A[(size_t)(M0 + ma) * K + k0 + ka];
        uint4 bv = *(const uint4*)&B[((size_t)(k0 + kb) << 10) + N0 + nb];
        const bf16* bp = (const bf16*)&bv;
#pragma unroll
        for (int j = 0; j < 8; ++j) Bs[(nb + j) * LDSPITCH + kb] = bp[j];
        __syncthreads();
        v8s a = *(v8s*)&As[(16 * w + (l & 15)) * LDSPITCH + (l >> 4) * 8];
#pragma unroll
        for (int nt = 0; nt < 4; ++nt) {
            v8s bf = *(v8s*)&Bs[(nt * 16 + (l & 15)) * LDSPITCH + (l >> 4) * 8];
            acc[nt] = __builtin_amdgcn_mfma_f32_16x16x32_bf16(a, bf, acc[nt], 0, 0, 0);
        }
    }
}

// ---- proj: acc -> bn1 -> + x -> x1f (fp32) and x1h (bf16) ------------------
__global__ __launch_bounds__(256) void k_gemm_proj(
        const bf16* __restrict__ A, const bf16* __restrict__ Ball,
        const float* __restrict__ x,
        const float* __restrict__ g1, const float* __restrict__ b1,
        const float* __restrict__ m1, const float* __restrict__ v1,
        float* __restrict__ x1f, bf16* __restrict__ x1h) {
    __shared__ bf16 As[64 * LDSPITCH], Bs[64 * LDSPITCH];
    int t = threadIdx.x, b = blockIdx.z;
    int N0 = blockIdx.x * 64, M0 = blockIdx.y * 64;
    v4f acc[4] = {};
    gemm_core(A, Ball + ((size_t)b * 512 << 10), 512, M0, N0, t, As, Bs, acc);
    int l = t & 63, w = t >> 6;
#pragma unroll
    for (int nt = 0; nt < 4; ++nt) {
        int col = N0 + nt * 16 + (l & 15);
#pragma unroll
        for (int r = 0; r < 4; ++r) {
            int row = M0 + 16 * w + ((l >> 4) << 2) + r;
            float sc = g1[row] / sqrtf(v1[row] + 1e-5f);
            size_t idx = (((size_t)b * 256 + row) << 10) + col;
            float val = (acc[nt][r] - m1[row]) * sc + b1[row] + x[idx];
            x1f[idx] = val;
            x1h[idx] = __float2bfloat16(val);
        }
    }
}

// ---- exp: acc + bias -> hswish -> h1 (bf16) --------------------------------
__global__ __launch_bounds__(256) void k_gemm_exp(
        const bf16* __restrict__ A, const bf16* __restrict__ Ball,
        const float* __restrict__ bias, bf16* __restrict__ h1) {
    __shared__ bf16 As[64 * LDSPITCH], Bs[64 * LDSPITCH];
    int t = threadIdx.x, b = blockIdx.z;
    int N0 = blockIdx.x * 64, M0 = blockIdx.y * 64;
    v4f acc[4] = {};
    gemm_core(A, Ball + ((size_t)b * 256 << 10), 256, M0, N0, t, As, Bs, acc);
    int l = t & 63, w = t >> 6;
#pragma unroll
    for (int nt = 0; nt < 4; ++nt) {
        int col = N0 + nt * 16 + (l & 15);
#pragma unroll
        for (int r = 0; r < 4; ++r) {
            int row = M0 + 16 * w + ((l >> 4) << 2) + r;
            float val = acc[nt][r] + bias[row];
            float hs  = val * fminf(fmaxf(val + 3.0f, 0.0f), 6.0f) * (1.0f / 6.0f);
            h1[(((size_t)b * EE + row) << 10) + col] = __float2bfloat16(hs);
        }
    }
}

// ---- pw: acc -> bn2 -> + x1f -> out (fp32) ---------------------------------
__global__ __launch_bounds__(256) void k_gemm_pw(
        const bf16* __restrict__ A, const bf16* __restrict__ Ball,
        const float* __restrict__ g2, const float* __restrict__ b2_,
        const float* __restrict__ m2, const float* __restrict__ v2,
        const float* __restrict__ x1f, float* __restrict__ out) {
    __shared__ bf16 As[64 * LDSPITCH], Bs[64 * LDSPITCH];
    int t = threadIdx.x, b = blockIdx.z;
    int N0 = blockIdx.x * 64, M0 = blockIdx.y * 64;
    v4f acc[4] = {};
    gemm_core(A, Ball + ((size_t)b * EE << 10), EE, M0, N0, t, As, Bs, acc);
    int l = t & 63, w = t >> 6;
#pragma unroll
    for (int nt = 0; nt < 4; ++nt) {
        int col = N0 + nt * 16 + (l & 15);
#pragma unroll
        for (int r = 0; r < 4; ++r) {
            int row = M0 + 16 * w + ((l >> 4) << 2) + r;
            float sc = g2[row] / sqrtf(v2[row] + 1e-5f);
            size_t idx = (((size_t)b * 256 + row) << 10) + col;
            out[idx] = (acc[nt][r] - m2[row]) * sc + b2_[row] + x1f[idx];
        }
    }
}

// ==================== K11: depthwise 3x3 + bias + hswish ====================
__global__ __launch_bounds__(256) void k_dw3(const bf16* __restrict__ h1,
                                             const float* __restrict__ w3,
                                             const float* __restrict__ bias,
                                             bf16* __restrict__ h2) {
    __shared__ float xs[10][32];
    __shared__ float wd[9];
    __shared__ float bsh;
    int t  = threadIdx.x;
    int rg = blockIdx.x;
    int e  = blockIdx.y;
    int b  = blockIdx.z;
    int r0 = rg * 8;
    const bf16* src = h1 + (((size_t)b * EE + e) << 10);
    for (int i = t; i < 320; i += 256) {
        int lr = i >> 5, c = i & 31;
        int ry = r0 + lr - 1;
        xs[lr][c] = (ry >= 0 && ry < 32) ? b2f(src[ry * 32 + c]) : 0.0f;
    }
    if (t < 9) wd[t] = w3[e * 9 + t];
    if (t == 9) bsh = bias[e];
    __syncthreads();
    int row = t >> 5, col = t & 31;
    float acc = bsh;
#pragma unroll
    for (int dy = 0; dy < 3; ++dy) {
#pragma unroll
        for (int dx = 0; dx < 3; ++dx) {
            int c = col + dx - 1;
            if (c >= 0 && c < 32)
                acc = fmaf(xs[row + dy][c], wd[dy * 3 + dx], acc);
        }
    }
    float hs = acc * fminf(fmaxf(acc + 3.0f, 0.0f), 6.0f) * (1.0f / 6.0f);
    h2[(((size_t)b * EE + e) << 10) + (r0 + row) * 32 + col] = __float2bfloat16(hs);
}

// ---------------------------------------------------------------------------
extern "C" void kernel_launch(void* const* d_in, const int* in_sizes, int n_in,
                              void* d_out, int out_size, void* d_ws, size_t ws_size,
                              hipStream_t stream) {
    const float* x      = (const float*)d_in[0];
    const float* w_qkv  = (const float*)d_in[1];
    const float* w_dw5  = (const float*)d_in[2];
    const float* w_pw_g = (const float*)d_in[3];
    const float* cb     = (const float*)d_in[4];
    const float* w_proj = (const float*)d_in[5];
    const float* bn1g   = (const float*)d_in[6];
    const float* bn1b   = (const float*)d_in[7];
    const float* bn1m   = (const float*)d_in[8];
    const float* bn1v   = (const float*)d_in[9];
    const float* w_exp  = (const float*)d_in[10];
    const float* b_exp  = (const float*)d_in[11];
    const float* w_dw3  = (const float*)d_in[12];
    const float* b_dw3  = (const float*)d_in[13];
    const float* w_pw   = (const float*)d_in[14];
    const float* bn2g   = (const float*)d_in[15];
    const float* bn2b   = (const float*)d_in[16];
    const float* bn2m   = (const float*)d_in[17];
    const float* bn2v   = (const float*)d_in[18];

    float* ws   = (float*)d_ws;
    float* qkvf = ws;                        // [0, 12582912)
    double* w64 = (double*)(ws + 12582912);  // [12582912, 12976128) pre-dwb
    float* dwb  = ws + 12582912;             // [12582912, 25165824)
    float* agg  = ws + 25165824;             // [25165824, 37748736)
    int*   qi   = (int*)(ws + 12582912);     // dead-dwb overlays:
    int*   ki   = (int*)(ws + 12845056);
    float* bkt  = ws + 13107200;             // [13107200, 15204352)
    bf16*  vout = (bf16*)(ws + 15204352);    // [15204352, 19398656)
    bf16*  wbp  = (bf16*)(ws);               // dead-qkvf overlays (post-scatter):
    bf16*  wbe  = (bf16*)(ws + 65536);
    bf16*  wbw  = (bf16*)(ws + 196608);
    float* x1f  = ws + 327680;               // [327680, 4521984)
    bf16*  x1h  = (bf16*)(ws + 4521984);     // [4521984, 6619136)
    bf16*  h2   = (bf16*)(ws + 6619136);     // [6619136, 15007744)
    bf16*  h1   = (bf16*)(ws + 25165824);    // dead-agg overlay

    k_cvt64  <<<768, 256, 0, stream>>>(w_qkv, w64);
    k_qkv    <<<dim3(4, 24, 16),  256, 0, stream>>>(x, w64, qkvf);
    k_dw5    <<<dim3(4, 768, 16), 256, 0, stream>>>(qkvf, w_dw5, dwb);
    k_gpw    <<<dim3(4, 24, 16),  256, 0, stream>>>(dwb, w_pw_g, agg);
    k_codes  <<<1024, 256, 0, stream>>>(qkvf, agg, cb, qi, ki);
    k_scatter<<<256, 512, 0, stream>>>(qkvf, agg, ki, bkt);
    k_cvt    <<<2560, 256, 0, stream>>>(w_proj, w_exp, w_pw, wbp, wbe, wbw);
    k_gather <<<32768, 256, 0, stream>>>(bkt, qi, vout);
    k_gemm_proj<<<dim3(16, 4, 16),  256, 0, stream>>>(wbp, vout, x,
                    bn1g, bn1b, bn1m, bn1v, x1f, x1h);
    k_gemm_exp <<<dim3(16, 16, 16), 256, 0, stream>>>(wbe, x1h, b_exp, h1);
    k_dw3    <<<dim3(4, 1024, 16), 256, 0, stream>>>(h1, w_dw3, b_dw3, h2);
    k_gemm_pw  <<<dim3(16, 4, 16),  256, 0, stream>>>(wbw, h2,
                    bn2g, bn2b, bn2m, bn2v, x1f, (float*)d_out);
}